// Round 1
// baseline (91.198 us; speedup 1.0000x reference)
//
#include <hip/hip_runtime.h>
#include <math.h>

// ---------------------------------------------------------------------------
// EEGGENET fused implementation.
//
// Shapes: B=64, C=64, T=1000, F1=8, D=2, F2=16, KLEN=64, NCLS=4.
// Tp = 1001 (temporal conv, pad 32).  Pool1 -> 125.  Downstream tiny.
//
// Algebra: s_bn2[b,oc,t] = sum_j Wf[oc][j] * p_conv  where the channel mix
// (graph conv + spatial conv + BN1 + BN2 scales) folds into Wf[48][64], and
// the channel contraction commutes with the temporal conv:
//   s[b,oc,t] = sum_q tw[f(oc),q] * ( sum_j Wf[oc][j] x[b,j,t-32+q] ) + bias[oc]
// so we compute p[oc][u] = Wf x (48x64 mix) first, then a 48-channel FIR.
// ---------------------------------------------------------------------------

#define EPS_BN 1e-3f

// workspace layout in floats
#define WF_OFF   0        // WfT[64][48]  (j-major, BN1*BN2 folded)
#define BIAS_OFF 3072     // bias[48]
#define A3_OFF   3120     // a3[16]
#define C3_OFF   3136     // c3[16]
#define CLS_OFF  3152     // renormed cls_w [4][240]
#define OUT1_OFF 4160     // pooled stage-1 output [64][48][125]
// total = 4160 + 384000 = 388160 floats = 1.55 MB

__global__ __launch_bounds__(256) void eeg_setup_kernel(
    const float* __restrict__ g1, const float* __restrict__ b1,
    const float* __restrict__ m1, const float* __restrict__ v1,
    const float* __restrict__ e1, const float* __restrict__ e2,
    const float* __restrict__ sw,
    const float* __restrict__ g2, const float* __restrict__ b2,
    const float* __restrict__ m2, const float* __restrict__ v2,
    const float* __restrict__ g3, const float* __restrict__ b3,
    const float* __restrict__ m3, const float* __restrict__ v3,
    const float* __restrict__ clsw, float* __restrict__ ws)
{
    __shared__ float A1[64][64];
    __shared__ float A2[64][64];
    __shared__ float rs1[64], rs2[64];
    __shared__ float swr[48][64];
    __shared__ float weff[48][64];
    __shared__ float snorm[48];
    __shared__ float csc[4];
    const int tid = threadIdx.x;

    // build adjacency A = tril(e) + tril(e)^T + I
    for (int idx = tid; idx < 4096; idx += 256) {
        int i = idx >> 6, j = idx & 63;
        float a1v, a2v;
        if (i == j) { a1v = 1.f; a2v = 1.f; }
        else {
            int ii = i > j ? i : j, jj = i > j ? j : i;
            int m = ii * (ii - 1) / 2 + jj;  // np.tril_indices(-1) row-major
            a1v = e1[m]; a2v = e2[m];
        }
        A1[i][j] = a1v; A2[i][j] = a2v;
    }
    // load spatial weights
    for (int idx = tid; idx < 3072; idx += 256) ((float*)swr)[idx] = sw[idx];
    __syncthreads();
    if (tid < 64) {  // row sums (normalization)
        float s1 = 0.f, s2 = 0.f;
        for (int j = 0; j < 64; ++j) { s1 += A1[tid][j]; s2 += A2[tid][j]; }
        rs1[tid] = 1.f / s1; rs2[tid] = 1.f / s2;
    }
    if (tid < 48) {  // spatial renorm, maxnorm = 1
        float n = 0.f;
        for (int j = 0; j < 64; ++j) n += swr[tid][j] * swr[tid][j];
        n = sqrtf(n);
        snorm[tid] = fminf(1.f, 1.f / fmaxf(n, 1e-7f));
    }
    __syncthreads();
    for (int idx = tid; idx < 3072; idx += 256)
        ((float*)swr)[idx] *= snorm[idx >> 6];
    __syncthreads();
    // W_eff[oc][j] = sum_c swr[oc][c] * Anorm_k[c][j]   (k=0 -> identity)
    for (int idx = tid; idx < 3072; idx += 256) {
        int oc = idx >> 6, j = idx & 63;
        int k = oc >> 4;
        float v;
        if (k == 0) v = swr[oc][j];
        else if (k == 1) {
            float acc = 0.f;
            for (int c = 0; c < 64; ++c) acc += swr[oc][c] * A1[c][j] * rs1[c];
            v = acc;
        } else {
            float acc = 0.f;
            for (int c = 0; c < 64; ++c) acc += swr[oc][c] * A2[c][j] * rs2[c];
            v = acc;
        }
        weff[oc][j] = v;
    }
    __syncthreads();
    // fold BN1 (per f) and BN2 (per oc); store transposed WfT[j][oc]
    for (int idx = tid; idx < 3072; idx += 256) {
        int oc = idx >> 6, j = idx & 63;
        int f = (oc >> 1) & 7;
        float a1 = g1[f] * rsqrtf(v1[f] + EPS_BN);
        float a2 = g2[oc] * rsqrtf(v2[oc] + EPS_BN);
        ws[WF_OFF + j * 48 + oc] = a2 * a1 * weff[oc][j];
    }
    if (tid < 48) {
        int oc = tid;
        float S = 0.f;
        for (int j = 0; j < 64; ++j) S += weff[oc][j];
        int f = (oc >> 1) & 7;
        float a1 = g1[f] * rsqrtf(v1[f] + EPS_BN);
        float c1 = b1[f] - m1[f] * a1;
        float a2 = g2[oc] * rsqrtf(v2[oc] + EPS_BN);
        float c2 = b2[oc] - m2[oc] * a2;
        ws[BIAS_OFF + oc] = a2 * c1 * S + c2;
    }
    if (tid < 16) {
        float a3 = g3[tid] * rsqrtf(v3[tid] + EPS_BN);
        ws[A3_OFF + tid] = a3;
        ws[C3_OFF + tid] = b3[tid] - m3[tid] * a3;
    }
    if (tid < 4) {  // classifier renorm, maxnorm = 0.25
        float n = 0.f;
        for (int j = 0; j < 240; ++j) { float w = clsw[tid * 240 + j]; n += w * w; }
        n = sqrtf(n);
        csc[tid] = fminf(1.f, 0.25f / fmaxf(n, 1e-7f));
    }
    __syncthreads();
    for (int idx = tid; idx < 960; idx += 256)
        ws[CLS_OFF + idx] = clsw[idx] * csc[idx / 240];
}

// ---------------------------------------------------------------------------
// Stage 1: per (b, tile of 24 pool outputs). Thread owns one x column.
//   p[oc][lu] = sum_j WfT[j][oc] * x[b][j][u0+lu]     (48 accs in regs)
//   then FIR(64) + bias + ELU + pool8 -> out1[b][oc][o]
// LDS: 63680 B -> 2 blocks/CU.
// ---------------------------------------------------------------------------
__global__ __launch_bounds__(256) void eeg_stage1_kernel(
    const float* __restrict__ x, const float* __restrict__ tw,
    const float* __restrict__ wcon, float* __restrict__ out1)
{
    __shared__ float WlT[64][48];
    __shared__ float twl[8][64];
    __shared__ float biasl[48];
    __shared__ float ps[48][256];
    const int tid = threadIdx.x;
    const int b = blockIdx.x / 6;
    const int tile = blockIdx.x % 6;
    const int o0 = tile * 24;
    const int no = (125 - o0) < 24 ? (125 - o0) : 24;
    const int u0 = 8 * o0 - 32;

    for (int i = tid; i < 3072; i += 256) ((float*)WlT)[i] = wcon[WF_OFF + i];
    for (int i = tid; i < 512; i += 256) ((float*)twl)[i] = tw[i];
    if (tid < 48) biasl[tid] = wcon[BIAS_OFF + tid];
    __syncthreads();

    {   // channel mix: this thread owns column u
        const int u = u0 + tid;
        const bool valid = (u >= 0) && (u < 1000);
        const float* xb = x + (size_t)b * 64000 + u;
        float acc[48];
#pragma unroll
        for (int oc = 0; oc < 48; ++oc) acc[oc] = 0.f;
#pragma unroll 4
        for (int j = 0; j < 64; ++j) {
            float xv = valid ? xb[j * 1000] : 0.f;
            const float4* wv = (const float4*)(&WlT[j][0]);
#pragma unroll
            for (int g = 0; g < 12; ++g) {
                float4 w = wv[g];
                acc[4 * g + 0] += w.x * xv;
                acc[4 * g + 1] += w.y * xv;
                acc[4 * g + 2] += w.z * xv;
                acc[4 * g + 3] += w.w * xv;
            }
        }
#pragma unroll
        for (int oc = 0; oc < 48; ++oc) ps[oc][tid] = acc[oc];
    }
    __syncthreads();

    // FIR(64) + ELU + pool8. task = (oc, pool group o)
    const int ntasks = 48 * no;
    for (int task = tid; task < ntasks; task += 256) {
        const int oc = task / no;
        const int o = task - oc * no;
        const int f = (oc >> 1) & 7;
        const int base = o * 8;
        float accv[8];
#pragma unroll
        for (int r = 0; r < 8; ++r) accv[r] = biasl[oc];
#pragma unroll
        for (int q0 = 0; q0 < 64; q0 += 8) {
            float win[16];
            const float4* pv = (const float4*)(&ps[oc][base + q0]);
#pragma unroll
            for (int g = 0; g < 4; ++g) {
                float4 v = pv[g];
                win[4 * g + 0] = v.x; win[4 * g + 1] = v.y;
                win[4 * g + 2] = v.z; win[4 * g + 3] = v.w;
            }
#pragma unroll
            for (int q = 0; q < 8; ++q) {
                float tv = twl[f][q0 + q];
#pragma unroll
                for (int r = 0; r < 8; ++r) accv[r] += tv * win[q + r];
            }
        }
        float s = 0.f;
#pragma unroll
        for (int r = 0; r < 8; ++r) {
            float v = accv[r];
            s += (v > 0.f) ? v : expm1f(v);
        }
        out1[((size_t)b * 48 + oc) * 125 + (o0 + o)] = s * 0.125f;
    }
}

// ---------------------------------------------------------------------------
// Stage 2: downstream per batch. dw conv(16,pad8) -> pw 48->16 -> BN3+ELU ->
// pool8 -> classifier. All in LDS (overlaid regions), 64 blocks.
// ---------------------------------------------------------------------------
#define SB_P1   0        // [48][125]  (reused for QQ [16][126])
#define SB_DWO  6000     // [48][126]  (reused for PL [16][15])
#define SB_DWL  12048    // [48][16]
#define SB_PWL  12816    // [16][48]
#define SB_CLS  13584    // [4][240]
#define SB_A3   14544    // [16]
#define SB_C3   14560    // [16]
#define SB_TOT  14576

__global__ __launch_bounds__(256) void eeg_stage2_kernel(
    const float* __restrict__ ws, const float* __restrict__ dww,
    const float* __restrict__ pww, const float* __restrict__ clsb,
    float* __restrict__ out)
{
    __shared__ float sb[SB_TOT];
    const int tid = threadIdx.x;
    const int b = blockIdx.x;
    const float* o1 = ws + OUT1_OFF + (size_t)b * 6000;

    for (int i = tid; i < 6000; i += 256) sb[SB_P1 + i] = o1[i];
    for (int i = tid; i < 768; i += 256) sb[SB_DWL + i] = dww[i];
    for (int i = tid; i < 768; i += 256) sb[SB_PWL + i] = pww[i];
    for (int i = tid; i < 960; i += 256) sb[SB_CLS + i] = ws[CLS_OFF + i];
    if (tid < 16) { sb[SB_A3 + tid] = ws[A3_OFF + tid]; sb[SB_C3 + tid] = ws[C3_OFF + tid]; }
    __syncthreads();

    // depthwise conv: K=16, pad 8, T 125 -> 126
    for (int idx = tid; idx < 48 * 126; idx += 256) {
        int ci = idx / 126, t = idx - ci * 126;
        float acc = 0.f;
#pragma unroll
        for (int r = 0; r < 16; ++r) {
            int tt = t - 8 + r;
            float xv = (tt >= 0 && tt < 125) ? sb[SB_P1 + ci * 125 + tt] : 0.f;
            acc += sb[SB_DWL + ci * 16 + r] * xv;
        }
        sb[SB_DWO + idx] = acc;
    }
    __syncthreads();
    // pointwise 48->16 + BN3 + ELU  (overwrites P1 region, disjoint from DWO)
    for (int idx = tid; idx < 16 * 126; idx += 256) {
        int co = idx / 126, t = idx - co * 126;
        float acc = 0.f;
#pragma unroll
        for (int ci = 0; ci < 48; ++ci)
            acc += sb[SB_PWL + co * 48 + ci] * sb[SB_DWO + ci * 126 + t];
        float v = sb[SB_A3 + co] * acc + sb[SB_C3 + co];
        sb[SB_P1 + idx] = (v > 0.f) ? v : expm1f(v);
    }
    __syncthreads();
    // pool8: 126 -> 15 (overwrites DWO region)
    for (int idx = tid; idx < 240; idx += 256) {
        int co = idx / 15, v = idx - co * 15;
        float s = 0.f;
#pragma unroll
        for (int r = 0; r < 8; ++r) s += sb[SB_P1 + co * 126 + v * 8 + r];
        sb[SB_DWO + idx] = s * 0.125f;
    }
    __syncthreads();
    if (tid < 4) {
        float acc = clsb[tid];
        for (int j = 0; j < 240; ++j)
            acc += sb[SB_CLS + tid * 240 + j] * sb[SB_DWO + j];
        out[(size_t)b * 4 + tid] = acc;
    }
}

extern "C" void kernel_launch(void* const* d_in, const int* in_sizes, int n_in,
                              void* d_out, int out_size, void* d_ws, size_t ws_size,
                              hipStream_t stream) {
    const float* x    = (const float*)d_in[0];
    const float* tw   = (const float*)d_in[1];
    const float* g1   = (const float*)d_in[2];
    const float* b1   = (const float*)d_in[3];
    const float* m1   = (const float*)d_in[4];
    const float* v1   = (const float*)d_in[5];
    const float* e1   = (const float*)d_in[6];
    const float* e2   = (const float*)d_in[7];
    const float* sw   = (const float*)d_in[8];
    const float* g2   = (const float*)d_in[9];
    const float* b2   = (const float*)d_in[10];
    const float* m2   = (const float*)d_in[11];
    const float* v2   = (const float*)d_in[12];
    const float* dww  = (const float*)d_in[13];
    const float* pww  = (const float*)d_in[14];
    const float* g3   = (const float*)d_in[15];
    const float* b3   = (const float*)d_in[16];
    const float* m3   = (const float*)d_in[17];
    const float* v3   = (const float*)d_in[18];
    const float* clsw = (const float*)d_in[19];
    const float* clsb = (const float*)d_in[20];
    float* ws = (float*)d_ws;
    float* out = (float*)d_out;

    eeg_setup_kernel<<<1, 256, 0, stream>>>(g1, b1, m1, v1, e1, e2, sw,
                                            g2, b2, m2, v2, g3, b3, m3, v3,
                                            clsw, ws);
    eeg_stage1_kernel<<<384, 256, 0, stream>>>(x, tw, ws, ws + OUT1_OFF);
    eeg_stage2_kernel<<<64, 256, 0, stream>>>(ws, dww, pww, clsb, out);
}

// Round 2
// 83.662 us; speedup vs baseline: 1.0901x; 1.0901x over previous
//
#include <hip/hip_runtime.h>
#include <math.h>

// ---------------------------------------------------------------------------
// EEGGENET fused implementation (round 2).
//
// Shapes: B=64, C=64, T=1000, F1=8, D=2, F2=16, KLEN=64, NCLS=4.
//
// Algebra: graph conv + spatial conv + BN1 + BN2 fold into Wf[48][64] applied
// to x columns; the channel contraction commutes with the temporal conv:
//   s[b,oc,t] = sum_q tw[f(oc),q] * ( sum_j Wf[oc][j] x[b,j,t-32+q] ) + bias[oc]
// Stage1: per (b, 8-output pool tile): mix 128 columns (48x64) into LDS, then
// FIR(64)+ELU+pool8. 1024 blocks, ~40KB LDS -> 4 blocks/CU.
// ---------------------------------------------------------------------------

#define EPS_BN 1e-3f

// workspace layout in floats
#define WF_OFF   0        // WfT[64][48]  (j-major, BN1*BN2 folded)
#define BIAS_OFF 3072     // bias[48]
#define A3_OFF   3120     // a3[16]
#define C3_OFF   3136     // c3[16]
#define CLS_OFF  3152     // renormed cls_w [4][240]
#define OUT1_OFF 4160     // pooled stage-1 output [64][48][125]
// total = 4160 + 384000 = 388160 floats = 1.55 MB

// ---------------------------------------------------------------------------
// Setup: 49 blocks. Blocks 0..47: one output channel each -> WfT column +
// bias. Block 48: BN3 affine + classifier renorm.
// ---------------------------------------------------------------------------
__global__ __launch_bounds__(256) void eeg_setup_kernel(
    const float* __restrict__ g1, const float* __restrict__ b1,
    const float* __restrict__ m1, const float* __restrict__ v1,
    const float* __restrict__ e1, const float* __restrict__ e2,
    const float* __restrict__ sw,
    const float* __restrict__ g2, const float* __restrict__ b2,
    const float* __restrict__ m2, const float* __restrict__ v2,
    const float* __restrict__ g3, const float* __restrict__ b3,
    const float* __restrict__ m3, const float* __restrict__ v3,
    const float* __restrict__ clsw, float* __restrict__ ws)
{
    const int tid = threadIdx.x;
    const int blk = blockIdx.x;

    if (blk < 48) {
        const int oc = blk;
        const int k = oc >> 4;          // hop: 0=identity, 1=A1, 2=A2
        __shared__ float A[64][65];
        __shared__ float rsl[64];
        __shared__ float swl[64];
        __shared__ float sred;

        if (k > 0) {
            const float* e = (k == 1) ? e1 : e2;
            for (int idx = tid; idx < 4096; idx += 256) {
                int i = idx >> 6, j = idx & 63;
                float v;
                if (i == j) v = 1.f;
                else {
                    int ii = i > j ? i : j, jj = i > j ? j : i;
                    v = e[ii * (ii - 1) / 2 + jj];
                }
                A[i][j] = v;
            }
        }
        if (tid < 64) swl[tid] = sw[oc * 64 + tid];
        __syncthreads();
        if (tid < 64) {
            if (k > 0) {
                float s = 0.f;
                for (int j = 0; j < 64; ++j) s += A[tid][j];
                rsl[tid] = 1.f / s;
            }
            float nv = swl[tid] * swl[tid];
            for (int off = 32; off; off >>= 1) nv += __shfl_down(nv, off);
            if (tid == 0) sred = nv;
        }
        __syncthreads();
        if (tid < 64) {
            const int j = tid;
            const float sn = fminf(1.f, 1.f / fmaxf(sqrtf(sred), 1e-7f));
            float w;
            if (k == 0) w = swl[j];
            else {
                float acc = 0.f;
                for (int c = 0; c < 64; ++c) acc += swl[c] * rsl[c] * A[c][j];
                w = acc;
            }
            w *= sn;
            const int f = (oc >> 1) & 7;
            const float a1 = g1[f] * rsqrtf(v1[f] + EPS_BN);
            const float a2 = g2[oc] * rsqrtf(v2[oc] + EPS_BN);
            ws[WF_OFF + j * 48 + oc] = a2 * a1 * w;
            float S = w;
            for (int off = 32; off; off >>= 1) S += __shfl_down(S, off);
            if (tid == 0) {
                const float c1 = b1[f] - m1[f] * a1;
                const float c2 = b2[oc] - m2[oc] * a2;
                ws[BIAS_OFF + oc] = a2 * c1 * S + c2;
            }
        }
    } else {
        __shared__ float csc[4];
        if (tid < 16) {
            const float a3 = g3[tid] * rsqrtf(v3[tid] + EPS_BN);
            ws[A3_OFF + tid] = a3;
            ws[C3_OFF + tid] = b3[tid] - m3[tid] * a3;
        }
        {   // classifier renorm (maxnorm 0.25): row = wave, 64 lanes/row
            const int row = tid >> 6, lane = tid & 63;
            float p = 0.f;
            if (row < 4)
                for (int idx = lane; idx < 240; idx += 64) {
                    float w = clsw[row * 240 + idx];
                    p += w * w;
                }
            for (int off = 32; off; off >>= 1) p += __shfl_down(p, off);
            if (row < 4 && lane == 0)
                csc[row] = fminf(1.f, 0.25f / fmaxf(sqrtf(p), 1e-7f));
        }
        __syncthreads();
        for (int idx = tid; idx < 960; idx += 256)
            ws[CLS_OFF + idx] = clsw[idx] * csc[idx / 240];
    }
}

// ---------------------------------------------------------------------------
// Stage 1: per (b, tile of 8 pool outputs) = 1024 blocks.
// Mix: 2 threads per column (24 ocs each) over 128 columns.
// FIR(64)+bias+ELU+pool8 -> out1. LDS 39.9 KB -> 4 blocks/CU.
// ---------------------------------------------------------------------------
__global__ __launch_bounds__(256, 4) void eeg_stage1_kernel(
    const float* __restrict__ x, const float* __restrict__ tw,
    const float* __restrict__ wcon, float* __restrict__ out1)
{
    __shared__ float WlT[64][48];
    __shared__ float twl[8][64];
    __shared__ float biasl[48];
    __shared__ float ps[48][132];   // pad 128->132: rotate banks per oc row
    const int tid = threadIdx.x;
    const int b = blockIdx.x >> 4;
    const int tile = blockIdx.x & 15;
    const int o0 = tile * 8;
    const int no = (125 - o0) < 8 ? (125 - o0) : 8;   // 8, last tile 5
    const int u0 = 8 * o0 - 32;

    for (int i = tid; i < 3072; i += 256) ((float*)WlT)[i] = wcon[WF_OFF + i];
    for (int i = tid; i < 512; i += 256) ((float*)twl)[i] = tw[i];
    if (tid < 48) biasl[tid] = wcon[BIAS_OFF + tid];
    __syncthreads();

    {   // channel mix: thread = (column ul, oc-half)
        const int ul = tid & 127;
        const int oc0 = (tid >> 7) * 24;
        const int u = u0 + ul;
        const bool valid = (u >= 0) && (u < 1000);
        const float* xb = x + (size_t)b * 64000 + u;
        float acc[24];
#pragma unroll
        for (int l = 0; l < 24; ++l) acc[l] = 0.f;
#pragma unroll 4
        for (int j = 0; j < 64; ++j) {
            float xv = valid ? xb[j * 1000] : 0.f;
            const float4* wv = (const float4*)(&WlT[j][oc0]);
#pragma unroll
            for (int g = 0; g < 6; ++g) {
                float4 w = wv[g];
                acc[4 * g + 0] += w.x * xv;
                acc[4 * g + 1] += w.y * xv;
                acc[4 * g + 2] += w.z * xv;
                acc[4 * g + 3] += w.w * xv;
            }
        }
#pragma unroll
        for (int l = 0; l < 24; ++l) ps[oc0 + l][ul] = acc[l];
    }
    __syncthreads();

    // FIR(64) + ELU + pool8. task = (oc, pool group o)
    const int ntasks = 48 * no;
    for (int task = tid; task < ntasks; task += 256) {
        const int oc = task / no;
        const int o = task - oc * no;
        const int f = (oc >> 1) & 7;
        const int base = o * 8;
        float accv[8];
#pragma unroll
        for (int r = 0; r < 8; ++r) accv[r] = biasl[oc];
#pragma unroll
        for (int q0 = 0; q0 < 64; q0 += 8) {
            float win[16];
            const float4* pv = (const float4*)(&ps[oc][base + q0]);
#pragma unroll
            for (int g = 0; g < 4; ++g) {
                float4 v = pv[g];
                win[4 * g + 0] = v.x; win[4 * g + 1] = v.y;
                win[4 * g + 2] = v.z; win[4 * g + 3] = v.w;
            }
#pragma unroll
            for (int q = 0; q < 8; ++q) {
                float tv = twl[f][q0 + q];
#pragma unroll
                for (int r = 0; r < 8; ++r) accv[r] += tv * win[q + r];
            }
        }
        float s = 0.f;
#pragma unroll
        for (int r = 0; r < 8; ++r) {
            float v = accv[r];
            s += (v > 0.f) ? v : expm1f(v);
        }
        out1[((size_t)b * 48 + oc) * 125 + (o0 + o)] = s * 0.125f;
    }
}

// ---------------------------------------------------------------------------
// Stage 2: downstream per batch. dw conv(16,pad8) -> pw 48->16 -> BN3+ELU ->
// pool8 -> classifier. All in LDS (overlaid regions), 64 blocks.
// ---------------------------------------------------------------------------
#define SB_P1   0        // [48][125]  (reused for QQ [16][126])
#define SB_DWO  6000     // [48][126]  (reused for PL [16][15])
#define SB_DWL  12048    // [48][16]
#define SB_PWL  12816    // [16][48]
#define SB_CLS  13584    // [4][240]
#define SB_A3   14544    // [16]
#define SB_C3   14560    // [16]
#define SB_TOT  14576

__global__ __launch_bounds__(256) void eeg_stage2_kernel(
    const float* __restrict__ ws, const float* __restrict__ dww,
    const float* __restrict__ pww, const float* __restrict__ clsb,
    float* __restrict__ out)
{
    __shared__ float sb[SB_TOT];
    const int tid = threadIdx.x;
    const int b = blockIdx.x;
    const float* o1 = ws + OUT1_OFF + (size_t)b * 6000;

    for (int i = tid; i < 6000; i += 256) sb[SB_P1 + i] = o1[i];
    for (int i = tid; i < 768; i += 256) sb[SB_DWL + i] = dww[i];
    for (int i = tid; i < 768; i += 256) sb[SB_PWL + i] = pww[i];
    for (int i = tid; i < 960; i += 256) sb[SB_CLS + i] = ws[CLS_OFF + i];
    if (tid < 16) { sb[SB_A3 + tid] = ws[A3_OFF + tid]; sb[SB_C3 + tid] = ws[C3_OFF + tid]; }
    __syncthreads();

    // depthwise conv: K=16, pad 8, T 125 -> 126
    for (int idx = tid; idx < 48 * 126; idx += 256) {
        int ci = idx / 126, t = idx - ci * 126;
        float acc = 0.f;
#pragma unroll
        for (int r = 0; r < 16; ++r) {
            int tt = t - 8 + r;
            float xv = (tt >= 0 && tt < 125) ? sb[SB_P1 + ci * 125 + tt] : 0.f;
            acc += sb[SB_DWL + ci * 16 + r] * xv;
        }
        sb[SB_DWO + idx] = acc;
    }
    __syncthreads();
    // pointwise 48->16 + BN3 + ELU  (overwrites P1 region, disjoint from DWO)
    for (int idx = tid; idx < 16 * 126; idx += 256) {
        int co = idx / 126, t = idx - co * 126;
        float acc = 0.f;
#pragma unroll
        for (int ci = 0; ci < 48; ++ci)
            acc += sb[SB_PWL + co * 48 + ci] * sb[SB_DWO + ci * 126 + t];
        float v = sb[SB_A3 + co] * acc + sb[SB_C3 + co];
        sb[SB_P1 + idx] = (v > 0.f) ? v : expm1f(v);
    }
    __syncthreads();
    // pool8: 126 -> 15 (overwrites DWO region)
    for (int idx = tid; idx < 240; idx += 256) {
        int co = idx / 15, v = idx - co * 15;
        float s = 0.f;
#pragma unroll
        for (int r = 0; r < 8; ++r) s += sb[SB_P1 + co * 126 + v * 8 + r];
        sb[SB_DWO + idx] = s * 0.125f;
    }
    __syncthreads();
    if (tid < 4) {
        float acc = clsb[tid];
        for (int j = 0; j < 240; ++j)
            acc += sb[SB_CLS + tid * 240 + j] * sb[SB_DWO + j];
        out[(size_t)b * 4 + tid] = acc;
    }
}

extern "C" void kernel_launch(void* const* d_in, const int* in_sizes, int n_in,
                              void* d_out, int out_size, void* d_ws, size_t ws_size,
                              hipStream_t stream) {
    const float* x    = (const float*)d_in[0];
    const float* tw   = (const float*)d_in[1];
    const float* g1   = (const float*)d_in[2];
    const float* b1   = (const float*)d_in[3];
    const float* m1   = (const float*)d_in[4];
    const float* v1   = (const float*)d_in[5];
    const float* e1   = (const float*)d_in[6];
    const float* e2   = (const float*)d_in[7];
    const float* sw   = (const float*)d_in[8];
    const float* g2   = (const float*)d_in[9];
    const float* b2   = (const float*)d_in[10];
    const float* m2   = (const float*)d_in[11];
    const float* v2   = (const float*)d_in[12];
    const float* dww  = (const float*)d_in[13];
    const float* pww  = (const float*)d_in[14];
    const float* g3   = (const float*)d_in[15];
    const float* b3   = (const float*)d_in[16];
    const float* m3   = (const float*)d_in[17];
    const float* v3   = (const float*)d_in[18];
    const float* clsw = (const float*)d_in[19];
    const float* clsb = (const float*)d_in[20];
    float* ws = (float*)d_ws;
    float* out = (float*)d_out;

    eeg_setup_kernel<<<49, 256, 0, stream>>>(g1, b1, m1, v1, e1, e2, sw,
                                             g2, b2, m2, v2, g3, b3, m3, v3,
                                             clsw, ws);
    eeg_stage1_kernel<<<1024, 256, 0, stream>>>(x, tw, ws, ws + OUT1_OFF);
    eeg_stage2_kernel<<<64, 256, 0, stream>>>(ws, dww, pww, clsb, out);
}